// Round 12
// baseline (33.163 us; speedup 1.0000x reference)
//
#include <hip/hip_runtime.h>

constexpr int N_NODES  = 4000000;
constexpr int N_GRAPHS = 4096;
constexpr int D_FEAT   = 8;
constexpr int N_CLS    = 10;
constexpr int CHUNK    = 512;                      // nodes per wave (×2 f4 = 1024, 64-f4 aligned)
constexpr int NCH      = (N_NODES + CHUNK - 1) / CHUNK;   // 7813 chunks
constexpr int ACC_F32  = N_GRAPHS * D_FEAT + N_GRAPHS;    // sums + counts = 36864 floats
constexpr int ZBLK     = ACC_F32 / (256 * 4);             // 36 blocks zero exactly ACC_F32

static_assert(ACC_F32 % (256 * 4) == 0, "zero region must tile exactly");

typedef float f32x4 __attribute__((ext_vector_type(4)));
typedef int   i32x4 __attribute__((ext_vector_type(4)));

// ws layout: [ sums 4096*8 f32 | cnts 4096 f32 | bounds 4097 i32 ]

// K1: linear boundary scan of ids (the only full ids read) + zero accumulators.
// Zero region [0, ACC_F32) never overlaps bounds (which starts at ACC_F32).
__global__ __launch_bounds__(256) void scan_zero(
    const i32x4* __restrict__ ids4, const int* __restrict__ ids,
    int* __restrict__ bounds, float* __restrict__ acc)
{
    if (blockIdx.x < ZBLK) {
        int z = (blockIdx.x * 256 + threadIdx.x) * 4;
        *(f32x4*)(acc + z) = (f32x4)(0.f);
    }

    int t = blockIdx.x * blockDim.x + threadIdx.x;
    int base = t * 4;
    if (base >= N_NODES) return;

    i32x4 v = ids4[t];
    int prev = (base == 0) ? -1 : ids[base - 1];   // neighbor's line: cache hit

    int cur;
    cur = v.x; if (cur != prev) { for (int g = prev + 1; g <= cur; ++g) bounds[g] = base + 0; } prev = cur;
    cur = v.y; if (cur != prev) { for (int g = prev + 1; g <= cur; ++g) bounds[g] = base + 1; } prev = cur;
    cur = v.z; if (cur != prev) { for (int g = prev + 1; g <= cur; ++g) bounds[g] = base + 2; } prev = cur;
    cur = v.w; if (cur != prev) { for (int g = prev + 1; g <= cur; ++g) bounds[g] = base + 3; } prev = cur;

    if (base + 4 >= N_NODES) {                     // close the tail
        for (int g = prev + 1; g <= N_GRAPHS; ++g) bounds[g] = N_NODES;
    }
}

// K2: waves own fixed aligned 512-node chunks; attribute spans via bounds taps.
__global__ __launch_bounds__(256, 8) void pool_atomic(
    const f32x4* __restrict__ xf,      // [N_NODES*2] flat float4 view of x
    const int*   __restrict__ ids,     // [N_NODES] (2 broadcast taps per wave)
    const int*   __restrict__ bounds,  // [N_GRAPHS+1]
    float*       __restrict__ sums,    // [N_GRAPHS*8]
    float*       __restrict__ cnts)    // [N_GRAPHS]
{
    int w = blockIdx.x * 4 + (threadIdx.x >> 6);
    if (w >= NCH) return;
    int lane = threadIdx.x & 63;

    int c0 = w * CHUNK;
    int c1 = min(c0 + CHUNK, N_NODES);
    int g0 = ids[c0];                  // wave-uniform broadcast loads
    int g1 = ids[c1 - 1];

    int p = c0, gcur = g0;
    while (true) {
        int pend = (gcur < g1) ? bounds[gcur + 1] : c1;   // uniform, L2-hot
        // accumulate span [p, pend): unit-stride f4, lane parity = feat half
        f32x4 a0 = (f32x4)(0.f), a1 = (f32x4)(0.f),
              a2 = (f32x4)(0.f), a3 = (f32x4)(0.f);
        int i = 2 * p + lane;
        int endf = 2 * pend;
        int full = (endf - 2 * p) >> 8;               // 256-f4 rounds
        for (int it = 0; it < full; ++it, i += 256) {
            a0 += xf[i];
            a1 += xf[i +  64];
            a2 += xf[i + 128];
            a3 += xf[i + 192];
        }
        for (; i < endf; i += 64) a0 += xf[i];        // exec-masked tail
        f32x4 acc = (a0 + a1) + (a2 + a3);

        // butterfly over even offsets: even lanes -> feats 0-3, odd -> 4-7
        #pragma unroll
        for (int off = 32; off >= 2; off >>= 1) {
            acc.x += __shfl_xor(acc.x, off);
            acc.y += __shfl_xor(acc.y, off);
            acc.z += __shfl_xor(acc.z, off);
            acc.w += __shfl_xor(acc.w, off);
        }
        // lane 0 holds feats 0-3, lane 1 holds feats 4-7: flush in parallel
        if (lane < 2 && pend > p) {
            float* s = sums + (size_t)gcur * D_FEAT + lane * 4;
            atomicAdd(s + 0, acc.x);
            atomicAdd(s + 1, acc.y);
            atomicAdd(s + 2, acc.z);
            atomicAdd(s + 3, acc.w);
        }
        if (lane == 0 && pend > p)
            atomicAdd(cnts + gcur, (float)(pend - p));

        if (pend >= c1) break;
        p = pend;
        ++gcur;                        // empty graphs -> zero-length spans, harmless
    }
}

// K3: mean + tiny linear epilogue.
__global__ __launch_bounds__(256) void finalize(
    const float* __restrict__ sums, const float* __restrict__ cnts,
    const float* __restrict__ W, const float* __restrict__ bias,
    float* __restrict__ out)
{
    int idx = blockIdx.x * blockDim.x + threadIdx.x;
    if (idx >= N_GRAPHS * N_CLS) return;
    int g = idx / N_CLS;
    int c = idx % N_CLS;
    float inv = 1.0f / cnts[g];
    const float* s = sums + (size_t)g * D_FEAT;
    const float* w = W + (size_t)c * D_FEAT;
    float a = bias[c];
    #pragma unroll
    for (int k = 0; k < D_FEAT; ++k)
        a += (s[k] * inv) * w[k];
    out[idx] = a;
}

extern "C" void kernel_launch(void* const* d_in, const int* in_sizes, int n_in,
                              void* d_out, int out_size, void* d_ws, size_t ws_size,
                              hipStream_t stream) {
    const float* x   = (const float*)d_in[0];   // [4M, 8] f32
    const int*   ids = (const int*)d_in[1];     // [4M] sorted segment ids
    // d_in[2] input_ids, d_in[3] attention_mask: unused by the forward
    const float* W   = (const float*)d_in[4];   // [10, 8]
    const float* b   = (const float*)d_in[5];   // [10]
    float*       out = (float*)d_out;           // [4096, 10]

    float* sums   = (float*)d_ws;
    float* cnts   = sums + (size_t)N_GRAPHS * D_FEAT;
    int*   bounds = (int*)(cnts + N_GRAPHS);

    int scan_blocks = (N_NODES / 4 + 255) / 256;          // 3907
    scan_zero<<<scan_blocks, 256, 0, stream>>>(
        (const i32x4*)ids, ids, bounds, sums);

    int pool_blocks = (NCH + 3) / 4;                      // 1954
    pool_atomic<<<pool_blocks, 256, 0, stream>>>(
        (const f32x4*)x, ids, bounds, sums, cnts);

    finalize<<<(N_GRAPHS * N_CLS + 255) / 256, 256, 0, stream>>>(
        sums, cnts, W, b, out);
}